// Round 5
// baseline (222.659 us; speedup 1.0000x reference)
//
#include <hip/hip_runtime.h>

// Problem constants (fixed by setup_inputs):
//   img:  [B=4, C=1, D=64, H=192, W=192]  fp32
//   flow: [B=4, 3,   D=64, H=192, W=192]  fp32
//   out:  [B=4, C=1, D=64, H=192, W=192]  fp32
#define B_  4
#define D_  64
#define H_  192
#define W_  192
#define HW_ (H_ * W_)
#define DHW_ (D_ * H_ * W_)

// Tile: one z-plane of 192 x TY outputs per workgroup, VEC=2 outputs/thread.
// VEC=2 -> lane-to-x stride 2 -> 2-way LDS bank aliasing (free, vs 8-way at VEC=4:
// row stride 192 and plane stride 2496 are both 0 mod 32, so bank == xb % 32).
// Window 13 x 8 x 192 = 78 KB -> exactly 2 workgroups/CU (159744 <= 163840 B).
// Halo is asymmetric because i* = (v+flow)*s - 0.5 biases floor() downward:
//   y: [Y-2, Y+10] for outputs [Y, Y+7];  z: [z-3, z+4] for output plane z.
#define VEC 2
#define TY 8
#define SY 13                   // staged rows per plane
#define SZ 8                    // staged planes
#define SPLANE (SY * W_)        // 2496 floats
#define SLDS (SZ * SPLANE)      // 19968 floats = 78 KB
#define TILE_OUT (W_ * TY)      // 1536 outputs
#define TPB (TILE_OUT / VEC)    // 768 threads = 12 waves
#define NWG_Y (H_ / TY)         // 24
#define NWG (B_ * D_ * NWG_Y)   // 6144 workgroups
#define CPLANE (SPLANE / 4)     // 624 f4 chunks per staged plane
#define NCHUNK (SLDS / 4)       // 4992 f4 chunks total

typedef float f4 __attribute__((ext_vector_type(4)));
typedef float f2 __attribute__((ext_vector_type(2)));
typedef f2 f2u __attribute__((aligned(4)));

__global__ __launch_bounds__(TPB, 6) void warp3d_kernel(
    const float* __restrict__ img,
    const float* __restrict__ flow,
    float* __restrict__ out)
{
    __shared__ float lds[SLDS];    // 78 KB -> 2 wg/CU

    int wg = blockIdx.x;
    int b  = wg / (D_ * NWG_Y);
    int rr = wg - b * (D_ * NWG_Y);
    int z  = rr / NWG_Y;
    int Y  = (rr - z * NWG_Y) * TY;

    int Zs = min(max(z - 3, 0), D_ - SZ);
    int Ys = min(max(Y - 2, 0), H_ - SY);

    const float* im = img + (size_t)b * DHW_;
    int t = threadIdx.x;

    // ---- stage 192x13x8 window into LDS ----
    // Each staged plane is SY consecutive rows -> 2496 contiguous floats in
    // global memory; f4 chunks never cross the block and are 16B aligned.
    {
        const float* src = im + Ys * W_;
        for (int idx = t; idx < NCHUNK; idx += TPB) {
            int j   = idx / CPLANE;
            int rem = idx - j * CPLANE;
            f4 v = *(const f4*)(src + (size_t)(Zs + j) * HW_ + rem * 4);
            *(f4*)(lds + j * SPLANE + rem * 4) = v;
        }
    }
    __syncthreads();

    // ---- this thread's 2 outputs (one z-plane, row-major) ----
    int o  = t * VEC;
    int x  = o % W_;
    int y  = Y + o / W_;

    size_t nbase = (size_t)b * DHW_ + ((size_t)z * H_ + y) * W_ + x;
    const float* fl = flow + (size_t)b * 3 * DHW_ + ((size_t)z * H_ + y) * W_ + x;
    f2 fx = __builtin_nontemporal_load((const f2u*)fl);
    f2 fy = __builtin_nontemporal_load((const f2u*)(fl + DHW_));
    f2 fz = __builtin_nontemporal_load((const f2u*)(fl + 2 * DHW_));

    const float sxc = (float)W_ / (float)(W_ - 1);
    const float syc = (float)H_ / (float)(H_ - 1);
    const float szc = (float)D_ / (float)(D_ - 1);

    f2 res;
#pragma unroll
    for (int i = 0; i < VEC; ++i) {
        float ix = ((float)(x + i) + fx[i]) * sxc - 0.5f;
        float iy = ((float)y + fy[i]) * syc - 0.5f;
        float iz = ((float)z + fz[i]) * szc - 0.5f;
        ix = fminf(fmaxf(ix, 0.0f), (float)(W_ - 1));
        iy = fminf(fmaxf(iy, 0.0f), (float)(H_ - 1));
        iz = fminf(fmaxf(iz, 0.0f), (float)(D_ - 1));

        float x0f = floorf(ix), y0f = floorf(iy), z0f = floorf(iz);
        float wx = ix - x0f, wy = iy - y0f, wz = iz - z0f;

        int x0 = (int)x0f, y0 = (int)y0f, z0 = (int)z0f;
        int xb = min(x0, W_ - 2);
        int hi = x0 - xb;                  // 1 only when x0 == W-1
        int y1 = min(y0 + 1, H_ - 1);
        int z1 = min(z0 + 1, D_ - 1);

        bool val = (y0 >= Ys) & (y1 <= Ys + SY - 1) &
                   (z0 >= Zs) & (z1 <= Zs + SZ - 1);

        float v000, v001, v010, v011, v100, v101, v110, v111;
        if (val) {
            int i00 = ((z0 - Zs) * SY + (y0 - Ys)) * W_ + xb;
            int i01 = ((z0 - Zs) * SY + (y1 - Ys)) * W_ + xb;
            int i10 = ((z1 - Zs) * SY + (y0 - Ys)) * W_ + xb;
            int i11 = ((z1 - Zs) * SY + (y1 - Ys)) * W_ + xb;
            v000 = lds[i00]; v001 = lds[i00 + 1];
            v010 = lds[i01]; v011 = lds[i01 + 1];
            v100 = lds[i10]; v101 = lds[i10 + 1];
            v110 = lds[i11]; v111 = lds[i11 + 1];
        } else {
            // exact fallback (~1.5% of samples), exec-masked
            f2 p00 = *(const f2u*)(im + (z0 * H_ + y0) * W_ + xb);
            f2 p01 = *(const f2u*)(im + (z0 * H_ + y1) * W_ + xb);
            f2 p10 = *(const f2u*)(im + (z1 * H_ + y0) * W_ + xb);
            f2 p11 = *(const f2u*)(im + (z1 * H_ + y1) * W_ + xb);
            v000 = p00.x; v001 = p00.y;
            v010 = p01.x; v011 = p01.y;
            v100 = p10.x; v101 = p10.y;
            v110 = p11.x; v111 = p11.y;
        }
        if (hi) { v000 = v001; v010 = v011; v100 = v101; v110 = v111; }

        float c00 = v000 + wx * (v001 - v000);
        float c01 = v010 + wx * (v011 - v010);
        float c10 = v100 + wx * (v101 - v100);
        float c11 = v110 + wx * (v111 - v110);
        float c0 = c00 + wy * (c01 - c00);
        float c1 = c10 + wy * (c11 - c10);
        res[i] = c0 + wz * (c1 - c0);
    }
    __builtin_nontemporal_store(res, (f2*)(out + nbase));
}

extern "C" void kernel_launch(void* const* d_in, const int* in_sizes, int n_in,
                              void* d_out, int out_size, void* d_ws, size_t ws_size,
                              hipStream_t stream) {
    const float* img  = (const float*)d_in[0];
    const float* flow = (const float*)d_in[1];
    float* out = (float*)d_out;

    warp3d_kernel<<<NWG, TPB, 0, stream>>>(img, flow, out);
}